// Round 1
// baseline (313.629 us; speedup 1.0000x reference)
//
#include <hip/hip_runtime.h>
#include <hip/hip_bf16.h>
#include <math.h>

#define T_ 768
#define D_ 64
#define TD (T_*D_)
#define EPSF 1e-8f

__device__ __forceinline__ float wave_sum64(float v) {
#pragma unroll
  for (int m = 32; m >= 1; m >>= 1) v += __shfl_xor(v, m, 64);
  return v;
}

__device__ __forceinline__ float sigmoidf_(float x) { return 1.0f / (1.0f + expf(-x)); }

// temps[l] = sigmoid(dot(basin, temp_w[l]) + temp_b[l]) + 0.5, l = 0..3
__global__ void temps_kernel(const float* __restrict__ basin,
                             const float* __restrict__ temp_w,
                             const float* __restrict__ temp_b,
                             float* __restrict__ temps) {
  int wave = threadIdx.x >> 6, lane = threadIdx.x & 63;
  float v = basin[lane] * temp_w[wave * 64 + lane];
  v = wave_sum64(v);
  if (lane == 0) temps[wave] = sigmoidf_(v + temp_b[wave]) + 0.5f;
}

// p = project_to_simplex(x) then renormalize (as in _qfi_attention_weights)
// one wave (64 threads) per token row
__global__ void p_kernel(const float* __restrict__ x, float* __restrict__ p) {
  int t = blockIdx.x, d = threadIdx.x;
  float v = x[t * 64 + d];
  // stable softplus: max(x,0) + log1p(exp(-|x|))
  float sp = fmaxf(v, 0.0f) + log1pf(expf(-fabsf(v)));
  float s = wave_sum64(sp);
  float p1 = sp / (s + EPSF);
  p1 = fmaxf(p1, EPSF);
  float s2 = wave_sum64(p1);
  p[t * 64 + d] = p1 / (s2 + EPSF);
}

// pass>0 feedback gate: x = x*g + prev*(1-g), g = sigmoid([x,prev] @ W^T + b)
// one wave per token; W is this layer's (64,128) row-major
__global__ void gate_kernel(const float* __restrict__ x_in,
                            const float* __restrict__ prev,
                            const float* __restrict__ W,
                            const float* __restrict__ b,
                            float* __restrict__ x_out) {
  __shared__ float xs[64], ps[64];
  int t = blockIdx.x, d = threadIdx.x;
  xs[d] = x_in[t * 64 + d];
  ps[d] = prev[t * 64 + d];
  __syncthreads();
  const float* w = W + d * 128;
  float acc = b[d];
#pragma unroll
  for (int k = 0; k < 64; k++) acc += xs[k] * w[k];
#pragma unroll
  for (int k = 0; k < 64; k++) acc += ps[k] * w[64 + k];
  float g = sigmoidf_(acc);
  x_out[t * 64 + d] = xs[d] * g + ps[d] * (1.0f - g);
}

// Fused QFI attention + residual for one output row i per block.
__global__ void __launch_bounds__(256)
attn_kernel(const float* __restrict__ x, const float* __restrict__ p,
            const float* __restrict__ temps, int layer,
            const float* __restrict__ rs_layers,
            float* __restrict__ x_out) {
  __shared__ float pi[64];
  __shared__ float lw[T_];
  __shared__ float red[256];
  __shared__ float accs[4][64];
  int i = blockIdx.x;
  int tid = threadIdx.x;
  if (tid < 64) pi[tid] = p[i * 64 + tid];
  __syncthreads();
  float inv_t = 1.0f / fmaxf(temps[layer], 1e-6f);

  // phase 1: logits
  for (int j = tid; j < T_; j += 256) {
    const float4* pj4 = reinterpret_cast<const float4*>(p + j * 64);
    float inner = 0.0f;
#pragma unroll
    for (int q = 0; q < 16; q++) {
      float4 v = pj4[q];
      inner += sqrtf(pi[q * 4 + 0] * v.x + EPSF);
      inner += sqrtf(pi[q * 4 + 1] * v.y + EPSF);
      inner += sqrtf(pi[q * 4 + 2] * v.z + EPSF);
      inner += sqrtf(pi[q * 4 + 3] * v.w + EPSF);
    }
    inner = fminf(fmaxf(inner, -1.0f + 1e-6f), 1.0f - 1e-6f);
    float dist = 2.0f * acosf(inner);
    lw[j] = -dist * inv_t;
  }
  __syncthreads();

  // max
  float m = -1e30f;
  for (int j = tid; j < T_; j += 256) m = fmaxf(m, lw[j]);
  red[tid] = m;
  __syncthreads();
  for (int s = 128; s > 0; s >>= 1) {
    if (tid < s) red[tid] = fmaxf(red[tid], red[tid + s]);
    __syncthreads();
  }
  float maxv = red[0];
  __syncthreads();

  // exp + sum
  float sum = 0.0f;
  for (int j = tid; j < T_; j += 256) {
    float e = expf(lw[j] - maxv);
    lw[j] = e;
    sum += e;
  }
  red[tid] = sum;
  __syncthreads();
  for (int s = 128; s > 0; s >>= 1) {
    if (tid < s) red[tid] += red[tid + s];
    __syncthreads();
  }
  float sumw = red[0];

  // phase 3: x_attn[i,d] = sum_j w_j * x[j,d]; 4 waves each take 192 j's
  int wave = tid >> 6, lane = tid & 63;
  float acc = 0.0f;
  int j0 = wave * 192;
  for (int j = j0; j < j0 + 192; j++) acc += lw[j] * x[j * 64 + lane];
  accs[wave][lane] = acc;
  __syncthreads();
  if (tid < 64) {
    float a = (accs[0][tid] + accs[1][tid] + accs[2][tid] + accs[3][tid]) / sumw;
    float xi = x[i * 64 + tid];
    float rs = rs_layers[layer];
    x_out[i * 64 + tid] = xi + rs * (a - xi);
  }
}

// between passes: pooled->MLP->agg, basin gate update (in place, LDS-staged)
__global__ void compress_kernel(const float* __restrict__ x, float* __restrict__ basin,
                                const float* __restrict__ w1, const float* __restrict__ b1,
                                const float* __restrict__ w2, const float* __restrict__ b2,
                                const float* __restrict__ uw, const float* __restrict__ ub) {
  __shared__ float part[4][64];
  __shared__ float pooled[64], h1[32], agg[64], bs[64];
  int wave = threadIdx.x >> 6, lane = threadIdx.x & 63;
  float acc = 0.0f;
  for (int t = wave; t < T_; t += 4) acc += x[t * 64 + lane];
  part[wave][lane] = acc;
  __syncthreads();
  if (threadIdx.x < 64) {
    pooled[threadIdx.x] = (part[0][threadIdx.x] + part[1][threadIdx.x] +
                           part[2][threadIdx.x] + part[3][threadIdx.x]) * (1.0f / T_);
    bs[threadIdx.x] = basin[threadIdx.x];
  }
  __syncthreads();
  if (threadIdx.x < 32) {
    float a = b1[threadIdx.x];
    for (int k = 0; k < 64; k++) a += w1[threadIdx.x * 64 + k] * pooled[k];
    h1[threadIdx.x] = tanhf(a);
  }
  __syncthreads();
  if (threadIdx.x < 64) {
    float a = b2[threadIdx.x];
    for (int k = 0; k < 32; k++) a += w2[threadIdx.x * 32 + k] * h1[k];
    agg[threadIdx.x] = tanhf(a);
  }
  __syncthreads();
  if (threadIdx.x < 64) {
    int o = threadIdx.x;
    float a = ub[o];
    for (int k = 0; k < 64; k++) a += uw[o * 128 + k] * bs[k];
    for (int k = 0; k < 64; k++) a += uw[o * 128 + 64 + k] * agg[k];
    float g = sigmoidf_(a);
    basin[o] = bs[o] * (1.0f - g) + agg[o] * g;
  }
}

__global__ void final_kernel(const float* __restrict__ x, const float* __restrict__ basin_seq,
                             const float* __restrict__ res_scale, float* __restrict__ out) {
  int idx = blockIdx.x * blockDim.x + threadIdx.x;
  if (idx < TD) {
    float xv = x[idx];
    out[idx] = xv + 0.01f * res_scale[0] * (xv - basin_seq[idx]);
  }
}

extern "C" void kernel_launch(void* const* d_in, const int* in_sizes, int n_in,
                              void* d_out, int out_size, void* d_ws, size_t ws_size,
                              hipStream_t stream) {
  const float* basin_seq    = (const float*)d_in[0];
  const float* basin_coords = (const float*)d_in[1];
  const float* temp_w       = (const float*)d_in[2];
  const float* temp_b       = (const float*)d_in[3];
  const float* rs_layers    = (const float*)d_in[4];
  const float* fb_w         = (const float*)d_in[5];   // (4,64,128)
  const float* fb_b         = (const float*)d_in[6];   // (4,64)
  const float* comp_w1      = (const float*)d_in[7];
  const float* comp_b1      = (const float*)d_in[8];
  const float* comp_w2      = (const float*)d_in[9];
  const float* comp_b2      = (const float*)d_in[10];
  const float* upd_w        = (const float*)d_in[11];
  const float* upd_b        = (const float*)d_in[12];
  const float* res_scale    = (const float*)d_in[13];
  float* out = (float*)d_out;

  float* ws = (float*)d_ws;
  float* prev[4];
  for (int l = 0; l < 4; l++) prev[l] = ws + l * TD;
  float* bufA  = ws + 4 * TD;
  float* bufB  = ws + 5 * TD;
  float* pbuf  = ws + 6 * TD;
  float* basin = ws + 7 * TD;   // 64
  float* temps = basin + 64;    // 4

  hipMemcpyAsync(bufA, basin_seq, TD * sizeof(float), hipMemcpyDeviceToDevice, stream);
  hipMemcpyAsync(basin, basin_coords, 64 * sizeof(float), hipMemcpyDeviceToDevice, stream);

  // ---- pass 0 ----
  temps_kernel<<<1, 256, 0, stream>>>(basin, temp_w, temp_b, temps);
  const float* x = bufA;
  for (int l = 0; l < 4; l++) {
    p_kernel<<<T_, 64, 0, stream>>>(x, pbuf);
    attn_kernel<<<T_, 256, 0, stream>>>(x, pbuf, temps, l, rs_layers, prev[l]);
    x = prev[l];
  }
  compress_kernel<<<1, 256, 0, stream>>>(x, basin, comp_w1, comp_b1, comp_w2, comp_b2,
                                         upd_w, upd_b);

  // ---- pass 1 ----
  temps_kernel<<<1, 256, 0, stream>>>(basin, temp_w, temp_b, temps);
  for (int l = 0; l < 4; l++) {
    gate_kernel<<<T_, 64, 0, stream>>>(x, prev[l], fb_w + l * 64 * 128, fb_b + l * 64, bufA);
    p_kernel<<<T_, 64, 0, stream>>>(bufA, pbuf);
    attn_kernel<<<T_, 256, 0, stream>>>(bufA, pbuf, temps, l, rs_layers, bufB);
    x = bufB;
  }

  final_kernel<<<(TD + 255) / 256, 256, 0, stream>>>(x, basin_seq, res_scale, out);
}